// Round 14
// baseline (182.966 us; speedup 1.0000x reference)
//
#include <hip/hip_runtime.h>
#include <hip/hip_bf16.h>
#include <stdint.h>

// Problem constants
#define BB   32
#define CIN  128
#define HH   64
#define WW   64
#define COUT 256
#define OHH  62
#define OWW  62
#define PIX_PER_B (OHH*OWW)        // 3844
#define NPIX (BB*PIX_PER_B)        // 123008 = 961 * 128
#define KTOT (9*CIN)               // 1152
#define WROW (KTOT*2)              // 2304 B per Wg row

typedef __bf16 bf16x8 __attribute__((ext_vector_type(8)));
typedef float  f32x4  __attribute__((ext_vector_type(4)));
typedef uint16_t u16x8 __attribute__((ext_vector_type(8)));

__device__ __forceinline__ uint16_t f2bf(float f) {
    uint32_t u = __float_as_uint(f);
    uint32_t r = (u + 0x7FFFu + ((u >> 16) & 1u)) >> 16;
    return (uint16_t)r;
}

__device__ __forceinline__ void gload_lds16(const void* g, void* l) {
    __builtin_amdgcn_global_load_lds(
        (const __attribute__((address_space(1))) uint32_t*)g,
        (__attribute__((address_space(3))) uint32_t*)l, 16, 0, 0);
}

// -------- Prepass 1: NCHW fp32 -> NHWC bf16 ----------------------------------
__global__ void __launch_bounds__(256) to_nhwc(const float* __restrict__ in,
                                               uint16_t* __restrict__ out) {
    int slab = blockIdx.x;            // b*64 + h
    int b = slab >> 6, h = slab & 63;
    int w  = threadIdx.x & 63;
    int cp = threadIdx.x >> 6;        // 0..3
    const float* src = in + (((size_t)b * CIN) * HH + h) * WW + w;
    uint16_t* dst = out + ((size_t)slab * WW + w) * CIN;
    #pragma unroll
    for (int it = 0; it < 4; ++it) {
        int c0 = cp * 32 + it * 8;
        u16x8 v;
        #pragma unroll
        for (int j = 0; j < 8; ++j) v[j] = f2bf(src[(c0 + j) * (HH * WW)]);
        *reinterpret_cast<u16x8*>(dst + c0) = v;
    }
}

// -------- Prepass 2: OIHW fp32 -> bf16 [o][uv*128 + c] -----------------------
__global__ void __launch_bounds__(256) pack_w(const float* __restrict__ w,
                                              uint16_t* __restrict__ out) {
    int idx = blockIdx.x * 256 + threadIdx.x;     // < 256*1152
    int o = idx / KTOT;
    int k = idx - o * KTOT;
    int uv = k >> 7, c = k & 127;
    out[idx] = f2bf(w[(o * CIN + c) * 9 + uv]);
}

// -------- Main: 128x128 tile, 4 waves (2Mx2N, 64x64 each) --------------------
// BARRIER-MINIMAL design: X operands are wave-private, loaded global->VGPR
// (each xf frag = 16 consecutive pixels x 64B = perfect L2 sectors), double-
// buffered across phases. Only A (weights) lives in LDS: 32KB per uv (128
// rows x 128c), ring-2, staged via gload_lds with r4's zero-conflict swizzle
// ([ph][row][64B], stored chunk = logical ^ ((row>>1)&3)). ONE barrier per uv
// (9 total, was 36): waves free-run across the 4 c-phases of each uv, fully
// decorrelating the {read-burst -> MFMA-burst} convoy that pinned MfmaUtil
// at 32% in rounds 1-13.
__global__ void __launch_bounds__(256, 3) conv_xreg(
        const uint16_t* __restrict__ Xg,   // NHWC bf16 [32][64][64][128]
        const uint16_t* __restrict__ Wg,   // bf16 [256][1152], k=(uv,c)
        const float*    __restrict__ bias, // [256]
        float*          __restrict__ out)  // NCHW fp32 [32][256][62][62]
{
    __shared__ char lds[2 * 32768 + 1024];
    int* pbase = (int*)(lds + 65536);   // [128] NHWC elem off of pixel
    int* obase = pbase + 128;           // [128] out flat base (o=0)

    const int tid  = threadIdx.x;
    const int lane = tid & 63;
    const int wid  = tid >> 6;          // 0..3

    // bijective XCD swizzle: nwg=1922, q=240, r=2
    int bid = blockIdx.x;
    int xcd = bid & 7, lid = bid >> 3;
    int swz = (xcd < 2 ? xcd * 241 : 482 + (xcd - 2) * 240) + lid;
    const int mt = swz & 1;             // c_out half (0..1)
    const int pt = swz >> 1;            // pixel tile (0..960)

    if (tid < 128) {
        int n   = pt * 128 + tid;
        int b   = n / PIX_PER_B;
        int rem = n - b * PIX_PER_B;
        int oh  = rem / OWW;
        int ow  = rem - oh * OWW;
        pbase[tid] = ((b * 64 + oh) * 64 + ow) * 128;
        obase[tid] = b * (COUT * PIX_PER_B) + rem;
    }
    __syncthreads();

    // ---- A staging (per uv, 32KB = 8 gload_lds16/thread) ----
    // LDS layout [ph 0..3][row 0..127][64B]; linear dst j*4096+tid*16 maps to
    // ph=j>>1, row=(j&1)*64+(tid>>2), stored chunk tid&3 which holds logical
    // chunk (tid&3)^((row>>1)&3) = (tid&3)^((tid>>3)&3).
    const int cs   = (((tid & 3) ^ ((tid >> 3) & 3)) << 4);
    const int ldst = tid * 16;
    const char* aL = (const char*)Wg + (mt * 128 + (tid >> 2)) * WROW + cs;
    const char* aH = aL + 64 * WROW;

    auto stageA = [&](int uv, char* slot) {
        int off = uv * 256;
        #pragma unroll
        for (int j = 0; j < 8; ++j) {
            const char* src = ((j & 1) ? aH : aL) + off + (j >> 1) * 64;
            gload_lds16(src, slot + j * 4096 + ldst);
        }
    };

    // ---- af read offsets (within one 8KB ph region; r4-proven, 0-conflict) --
    const int wm = wid >> 1, wn = wid & 1;   // 2 M-waves x 2 N-waves
    int aoff[4];
    #pragma unroll
    for (int mi = 0; mi < 4; ++mi) {
        int row = wm * 64 + mi * 16 + (lane & 15);
        aoff[mi] = row * 64 + ((((lane >> 4) ^ ((row >> 1) & 3))) << 4);
    }

    // ---- X per-lane frag bases: pixel = wn*64+nj*16+(lane&15), k-chunk
    // byte = (lane>>4)*16 within each 64B (32c) phase slice ----
    const char* xb[4];
    #pragma unroll
    for (int nj = 0; nj < 4; ++nj) {
        int p = wn * 64 + nj * 16 + (lane & 15);
        xb[nj] = (const char*)Xg + (size_t)pbase[p] * 2 + ((lane >> 4) << 4);
    }

    f32x4 acc[4][4] = {};
    bf16x8 xfA[4], xfB[4];
    char* s0 = lds;
    char* s1 = lds + 32768;

// One c-phase: optionally prefetch next phase's X into XN (global->VGPR,
// compiler inserts the vmcnt before first use); read af(PH) from SLOTP;
// 16 MFMA on (af, XC).
#define PHX(SLOTP, PH, XC, XN, DOPRE, PREOFF) do {                             \
    if (DOPRE) { _Pragma("unroll") for (int nj = 0; nj < 4; ++nj)              \
        XN[nj] = *reinterpret_cast<const bf16x8*>(xb[nj] + (PREOFF)); }        \
    bf16x8 af[4];                                                              \
    _Pragma("unroll") for (int mi = 0; mi < 4; ++mi)                           \
        af[mi] = *reinterpret_cast<const bf16x8*>(                             \
            (SLOTP) + (PH) * 8192 + aoff[mi]);                                 \
    __builtin_amdgcn_s_setprio(1);                                             \
    _Pragma("unroll") for (int mi = 0; mi < 4; ++mi)                           \
      _Pragma("unroll") for (int nj = 0; nj < 4; ++nj)                         \
        acc[mi][nj] = __builtin_amdgcn_mfma_f32_16x16x32_bf16(                 \
            af[mi], XC[nj], acc[mi][nj], 0, 0, 0);                             \
    __builtin_amdgcn_s_setprio(0);                                             \
} while (0)

    // ---- prologue: stage A(0); prefetch X(uv0, ph0) ----
    stageA(0, s0);
    #pragma unroll
    for (int nj = 0; nj < 4; ++nj)
        xfA[nj] = *reinterpret_cast<const bf16x8*>(xb[nj]);
    asm volatile("s_waitcnt vmcnt(0)" ::: "memory");
    __builtin_amdgcn_s_barrier();

    // ---- main: 9 uv iterations x 4 c-phases; ONE barrier per uv ----
    #pragma unroll
    for (int uv = 0; uv < 9; ++uv) {
        char* sc = (uv & 1) ? s1 : s0;
        char* sn = (uv & 1) ? s0 : s1;
        const int u  = uv / 3, v = uv - (uv / 3) * 3;     // compile-time
        const int xo = (u << 14) | (v << 8);
        const int un = uv + 1;
        const int nxo = ((un / 3) << 14) | ((un - (un / 3) * 3) << 8);
        if (uv < 8) stageA(uv + 1, sn);
        PHX(sc, 0, xfA, xfB, 1, xo + 64);
        PHX(sc, 1, xfB, xfA, 1, xo + 128);
        PHX(sc, 2, xfA, xfB, 1, xo + 192);
        PHX(sc, 3, xfB, xfA, (uv < 8), nxo);
        if (uv < 8) {
            asm volatile("s_waitcnt vmcnt(0)" ::: "memory");  // A(uv+1) staged
            __builtin_amdgcn_s_barrier();
        }
    }
#undef PHX

    // ---- epilogue: C/D col=lane&15 (pixel), row=(lane>>4)*4+reg (o) ----
    #pragma unroll
    for (int mi = 0; mi < 4; ++mi) {
        int o = mt * 128 + wm * 64 + mi * 16 + ((lane >> 4) << 2);
        #pragma unroll
        for (int reg = 0; reg < 4; ++reg) {
            float bv = bias[o + reg];
            #pragma unroll
            for (int nj = 0; nj < 4; ++nj) {
                int pl = wn * 64 + nj * 16 + (lane & 15);
                out[obase[pl] + (o + reg) * PIX_PER_B] = acc[mi][nj][reg] + bv;
            }
        }
    }
}

// -------- Fallback (ws too small): naive direct conv -------------------------
__global__ void __launch_bounds__(256) conv_naive(const float* __restrict__ in,
                                                  const float* __restrict__ w,
                                                  const float* __restrict__ bias,
                                                  float* __restrict__ out) {
    long idx = (long)blockIdx.x * 256 + threadIdx.x;
    int t = (int)idx;
    int ow = t % OWW; t /= OWW;
    int oh = t % OHH; t /= OHH;
    int o  = t % COUT;
    int b  = t / COUT;
    float s = bias[o];
    for (int c = 0; c < CIN; ++c)
        for (int u = 0; u < 3; ++u)
            for (int v = 0; v < 3; ++v)
                s += in[((b * CIN + c) * HH + oh + u) * WW + ow + v] *
                     w[((o * CIN + c) * 3 + u) * 3 + v];
    out[idx] = s;
}

extern "C" void kernel_launch(void* const* d_in, const int* in_sizes, int n_in,
                              void* d_out, int out_size, void* d_ws, size_t ws_size,
                              hipStream_t stream) {
    const float* in   = (const float*)d_in[0];
    const float* wt   = (const float*)d_in[1];
    const float* bias = (const float*)d_in[2];
    float* out = (float*)d_out;

    const size_t xg_elems = (size_t)BB * HH * WW * CIN;       // 33.5M bf16
    const size_t wg_elems = (size_t)COUT * KTOT;              // 295K bf16
    const size_t need = (xg_elems + wg_elems) * sizeof(uint16_t);

    if (ws_size < need) {
        long total = (long)BB * COUT * OHH * OWW;
        conv_naive<<<(int)((total + 255) / 256), 256, 0, stream>>>(in, wt, bias, out);
        return;
    }

    uint16_t* Xg = (uint16_t*)d_ws;
    uint16_t* Wg = Xg + xg_elems;

    to_nhwc<<<BB * HH, 256, 0, stream>>>(in, Xg);
    pack_w<<<(COUT * KTOT) / 256, 256, 0, stream>>>(wt, Wg);
    conv_xreg<<<2 * (NPIX / 128), 256, 0, stream>>>(Xg, Wg, bias, out);
}